// Round 6
// baseline (330.627 us; speedup 1.0000x reference)
//
#include <hip/hip_runtime.h>
#include <hip/hip_bf16.h>
#include <stdint.h>

typedef __attribute__((ext_vector_type(4))) float f32x4;
typedef __attribute__((ext_vector_type(8))) _Float16 f16x8;
typedef __attribute__((ext_vector_type(2))) __fp16 fp16x2;

#define NB 32
#define MM 1024
#define DD 128
#define BKV 64
#define HTILE 8            // tiles per half (512 kv / 64)
#define LOG2E 1.44269504089f
#define RTHR 6.0f

static constexpr size_t ARR = (size_t)NB * MM * DD;  // elems per f16 array

// ws layout (f16): Ah @0, Bh @ARR, ATh @2*ARR, BTh @3*ARR
// Row-major Xh[b][r][128]: 16B chunk c of row r at in-row byte (c*16) ^ ((r&7)<<4)
// Transposed XTh[b][d][1024]: per 64-kv (128B) window, chunk c at (c*16) ^ ((d&7)<<4),
//   kv positions sigma_V-permuted (prep phase 2).

__device__ __forceinline__ float fexp2(float x) { return __builtin_amdgcn_exp2f(x); }

__device__ __forceinline__ void gl16(const void* g, void* l) {
  __builtin_amdgcn_global_load_lds((const __attribute__((address_space(1))) void*)g,
                                   (__attribute__((address_space(3))) void*)l, 16, 0, 0);
}

__global__ __launch_bounds__(256) void prep_kernel(const float* __restrict__ A,
                                                   const float* __restrict__ B,
                                                   _Float16* __restrict__ ws) {
  const int rt = blockIdx.x;     // 64-row tile
  const int b  = blockIdx.y;
  const int wh = blockIdx.z;     // 0=A, 1=B
  const float* __restrict__ src = wh ? B : A;
  _Float16* __restrict__ Xh  = ws + (size_t)wh * ARR;
  _Float16* __restrict__ XTh = ws + 2 * ARR + (size_t)wh * ARR;

  __shared__ __align__(16) _Float16 tile[64][130];
  const int t = threadIdx.x;

#pragma unroll
  for (int it = 0; it < 4; ++it) {
    int id  = it * 256 + t;
    int row = id >> 4;
    int ch  = id & 15;
    int grow = rt * 64 + row;
    const float* p = src + ((size_t)(b * MM + grow) * DD + ch * 8);
    float4 x0 = *(const float4*)p;
    float4 x1 = *(const float4*)(p + 4);
    f16x8 h;
    h[0] = (_Float16)x0.x; h[1] = (_Float16)x0.y; h[2] = (_Float16)x0.z; h[3] = (_Float16)x0.w;
    h[4] = (_Float16)x1.x; h[5] = (_Float16)x1.y; h[6] = (_Float16)x1.z; h[7] = (_Float16)x1.w;
    char* dst = (char*)Xh + (((size_t)(b * MM + grow)) << 8) + ((ch << 4) ^ ((row & 7) << 4));
    *(f16x8*)dst = h;
#pragma unroll
    for (int j = 0; j < 8; ++j) tile[row][ch * 8 + j] = h[j];
  }
  __syncthreads();

  // sigma_V(i): out5=i5, out4=i2, out3=i4, out2=i3, out1:0=i1:0
#pragma unroll
  for (int it = 0; it < 4; ++it) {
    int id = it * 256 + t;
    int d  = id >> 3;
    int ch = id & 7;
    f16x8 h;
#pragma unroll
    for (int j = 0; j < 8; ++j) {
      int i = ch * 8 + j;
      int s = (i & 0x23) | ((i & 4) << 2) | ((i & 24) >> 1);
      h[j] = tile[s][d];
    }
    char* dst = (char*)XTh + (((size_t)(b * DD + d)) << 11) + (rt << 7)
              + ((ch << 4) ^ ((d & 7) << 4));
    *(f16x8*)dst = h;
  }
}

union SMem {
  char stage[2][2][32768];                     // [half][buf][ K 16KB | V 16KB ]  = 128 KB
  struct {
    float O1[256][136];                        // half-1 unnormalized O, padded rows
    float m1[256];
    float l1[256];
  } mrg;                                       // 141 KB
};

__global__ __launch_bounds__(1024, 4) void attn_kernel(const _Float16* __restrict__ ws,
                                                       float* __restrict__ out) {
  // blockIdx = qt*64 + (dir*32 + b): all blocks of batch b share an XCD
  const int g   = blockIdx.x;        // 0..255
  const int qt  = g >> 6;            // 0..3 (256-row Q tile)
  const int rem = g & 63;
  const int dir = rem >> 5;
  const int b   = rem & 31;

  const _Float16* __restrict__ Qh  = ws + (dir ? ARR : 0);
  const _Float16* __restrict__ Kh  = ws + (dir ? 0 : ARR);
  const _Float16* __restrict__ VTh = ws + 2 * ARR + (dir ? 0 : ARR);
  float* __restrict__ outp = out + (size_t)dir * ARR;

  __shared__ __align__(16) SMem sm;

  const int tid  = threadIdx.x;
  const int w    = tid >> 6;         // 0..15
  const int half = w >> 3;           // 0: kv 0..511, 1: kv 512..1023
  const int wl   = w & 7;            // wave within half
  const int ht   = tid & 511;        // thread within half
  const int lane = tid & 63;
  const int lrow = lane & 15;
  const int lgrp = lane >> 4;

  const int qloc = wl * 32 + lrow;             // 0..255 (block-local q), qb adds 16
  const int q0   = qt * 256 + qloc;            // global q row

  // ---- Q B-fragments (both q-blocks)
  f16x8 qf[2][4];
  {
    const int swz = (lrow & 7) << 4;
#pragma unroll
    for (int qb = 0; qb < 2; ++qb) {
      const char* qbase = (const char*)Qh + (((size_t)(b * MM + q0 + qb * 16)) << 8);
#pragma unroll
      for (int kc = 0; kc < 4; ++kc)
        qf[qb][kc] = *(const f16x8*)(qbase + ((kc * 64 + lgrp * 16) ^ swz));
    }
  }

  // ---- per-lane LDS byte offsets within this half's buffer (swizzle folded)
  const int pl  = (lgrp * 16) ^ ((lrow & 3) << 4);
  const int lb6 = (lrow & 4) << 4;
  const int kE = lrow * 256 + pl + lb6;
  const int kO = lrow * 256 + pl + (64 - lb6);
  const int vE = 16384 + lrow * 128 + pl + lb6;
  const int vO = 16384 + lrow * 128 + pl + (64 - lb6);

  // ---- staging source bases (per thread-in-half); half offsets kv by 512
  const char* ksrc = (const char*)Kh + (((size_t)(b * MM + half * 512)) << 8) + (size_t)ht * 16;
  const char* vsrc = (const char*)VTh + (((size_t)(b * DD)) << 11) + (size_t)(half * 512) * 2
                   + ((size_t)(ht >> 3) << 11) + (size_t)(ht & 7) * 16;

  f32x4 oacc[2][8];
#pragma unroll
  for (int qb = 0; qb < 2; ++qb)
#pragma unroll
    for (int dt = 0; dt < 8; ++dt) oacc[qb][dt] = (f32x4)0.0f;
  float mrun[2] = {-1e30f, -1e30f};
  float lrun[2] = {0.0f, 0.0f};

  f16x8 vreg[16];
  f16x8 pf[2][2];

  // prologue: stage tile 0 of this half (K: 2 gl16, V: 2 gl16 per thread)
  {
    char* sb = sm.stage[half][0];
#pragma unroll
    for (int it = 0; it < 2; ++it)
      gl16(ksrc + it * 8192, sb + it * 8192 + ht * 16);
#pragma unroll
    for (int it = 0; it < 2; ++it)
      gl16(vsrc + (size_t)it * 131072, sb + 16384 + it * 8192 + ht * 16);
  }
  asm volatile("s_waitcnt vmcnt(0)" ::: "memory");
  __syncthreads();

#pragma unroll 1
  for (int t = 0; t < HTILE; ++t) {
    const char* base = sm.stage[half][t & 1];

    // 1. issue next tile's staging
    if (t + 1 < HTILE) {
      char* sb = sm.stage[half][(t + 1) & 1];
      const char* kp = ksrc + (size_t)(t + 1) * 16384;
      const char* vp = vsrc + (size_t)(t + 1) * 128;
#pragma unroll
      for (int it = 0; it < 2; ++it)
        gl16(kp + it * 8192, sb + it * 8192 + ht * 16);
#pragma unroll
      for (int it = 0; it < 2; ++it)
        gl16(vp + (size_t)it * 131072, sb + 16384 + it * 8192 + ht * 16);
    }

    // 2a. S^T = mfma(K, Q)
    f32x4 sc[2][4];
#pragma unroll
    for (int qb = 0; qb < 2; ++qb)
#pragma unroll
      for (int nt = 0; nt < 4; ++nt) sc[qb][nt] = (f32x4)0.0f;
    __builtin_amdgcn_s_setprio(1);
#pragma unroll
    for (int nt = 0; nt < 4; ++nt) {
#pragma unroll
      for (int kc = 0; kc < 4; ++kc) {
        const int off = ((kc & 1) ? kO + (kc - 1) * 64 : kE + kc * 64) + nt * 4096;
        f16x8 kf = *(const f16x8*)(base + off);
        sc[0][nt] = __builtin_amdgcn_mfma_f32_16x16x32_f16(kf, qf[0][kc], sc[0][nt], 0, 0, 0);
        sc[1][nt] = __builtin_amdgcn_mfma_f32_16x16x32_f16(kf, qf[1][kc], sc[1][nt], 0, 0, 0);
      }
    }

    // 2b. PV(t-1) from registers
    if (t > 0) {
#pragma unroll
      for (int dt = 0; dt < 8; ++dt) {
        oacc[0][dt] = __builtin_amdgcn_mfma_f32_16x16x32_f16(vreg[dt * 2 + 0], pf[0][0], oacc[0][dt], 0, 0, 0);
        oacc[0][dt] = __builtin_amdgcn_mfma_f32_16x16x32_f16(vreg[dt * 2 + 1], pf[0][1], oacc[0][dt], 0, 0, 0);
        oacc[1][dt] = __builtin_amdgcn_mfma_f32_16x16x32_f16(vreg[dt * 2 + 0], pf[1][0], oacc[1][dt], 0, 0, 0);
        oacc[1][dt] = __builtin_amdgcn_mfma_f32_16x16x32_f16(vreg[dt * 2 + 1], pf[1][1], oacc[1][dt], 0, 0, 0);
      }
    }
    __builtin_amdgcn_s_setprio(0);

    // 3. softmax: in-lane max, cross-lane only on trigger
    float mx[2];
#pragma unroll
    for (int qb = 0; qb < 2; ++qb) {
      float a0 = fmaxf(fmaxf(sc[qb][0][0], sc[qb][0][1]), fmaxf(sc[qb][0][2], sc[qb][0][3]));
      float a1 = fmaxf(fmaxf(sc[qb][1][0], sc[qb][1][1]), fmaxf(sc[qb][1][2], sc[qb][1][3]));
      float a2 = fmaxf(fmaxf(sc[qb][2][0], sc[qb][2][1]), fmaxf(sc[qb][2][2], sc[qb][2][3]));
      float a3 = fmaxf(fmaxf(sc[qb][3][0], sc[qb][3][1]), fmaxf(sc[qb][3][2], sc[qb][3][3]));
      mx[qb] = fmaxf(fmaxf(a0, a1), fmaxf(a2, a3));
    }
    bool need = (mx[0] > mrun[0] + RTHR) || (mx[1] > mrun[1] + RTHR);
    if (__any(need)) {
#pragma unroll
      for (int qb = 0; qb < 2; ++qb) {
        float cm = mx[qb];
        cm = fmaxf(cm, __shfl_xor(cm, 16));
        cm = fmaxf(cm, __shfl_xor(cm, 32));
        float mnew = fmaxf(mrun[qb], cm);
        float scale = fexp2((mrun[qb] - mnew) * LOG2E);
        lrun[qb] *= scale;
#pragma unroll
        for (int dt = 0; dt < 8; ++dt) oacc[qb][dt] *= scale;
        mrun[qb] = mnew;
      }
    }

    // 4. P = exp(S-m), pack in-register (sigma_V aligned)
#pragma unroll
    for (int qb = 0; qb < 2; ++qb) {
      union { fp16x2 h[8]; f16x8 v[2]; } u;
      float ps = 0.0f;
      const float nml = -mrun[qb] * LOG2E;
#pragma unroll
      for (int nt = 0; nt < 4; ++nt) {
        float p0 = fexp2(fmaf(sc[qb][nt][0], LOG2E, nml));
        float p1 = fexp2(fmaf(sc[qb][nt][1], LOG2E, nml));
        float p2 = fexp2(fmaf(sc[qb][nt][2], LOG2E, nml));
        float p3 = fexp2(fmaf(sc[qb][nt][3], LOG2E, nml));
        ps += (p0 + p1) + (p2 + p3);
        u.h[nt * 2 + 0] = __builtin_amdgcn_cvt_pkrtz(p0, p1);
        u.h[nt * 2 + 1] = __builtin_amdgcn_cvt_pkrtz(p2, p3);
      }
      lrun[qb] += ps;
      pf[qb][0] = u.v[0];
      pf[qb][1] = u.v[1];
    }

    // 5. V(t) LDS -> registers (consumed by PV next iter)
#pragma unroll
    for (int dt = 0; dt < 8; ++dt) {
      vreg[dt * 2 + 0] = *(const f16x8*)(base + vE + dt * 2048);
      vreg[dt * 2 + 1] = *(const f16x8*)(base + vO + dt * 2048);
    }

    asm volatile("s_waitcnt vmcnt(0)" ::: "memory");
    __syncthreads();
  }

  // ---- drain PV(last)
#pragma unroll
  for (int dt = 0; dt < 8; ++dt) {
    oacc[0][dt] = __builtin_amdgcn_mfma_f32_16x16x32_f16(vreg[dt * 2 + 0], pf[0][0], oacc[0][dt], 0, 0, 0);
    oacc[0][dt] = __builtin_amdgcn_mfma_f32_16x16x32_f16(vreg[dt * 2 + 1], pf[0][1], oacc[0][dt], 0, 0, 0);
    oacc[1][dt] = __builtin_amdgcn_mfma_f32_16x16x32_f16(vreg[dt * 2 + 0], pf[1][0], oacc[1][dt], 0, 0, 0);
    oacc[1][dt] = __builtin_amdgcn_mfma_f32_16x16x32_f16(vreg[dt * 2 + 1], pf[1][1], oacc[1][dt], 0, 0, 0);
  }

  // ---- combine per-lane l within each half
  float lsum[2];
#pragma unroll
  for (int qb = 0; qb < 2; ++qb) {
    float l = lrun[qb];
    l += __shfl_xor(l, 16);
    l += __shfl_xor(l, 32);
    lsum[qb] = l;
  }

  // ---- half 1 publishes unnormalized O, m, l to LDS (stage area is dead)
  __syncthreads();   // all stage reads complete before overwrite
  if (half == 1) {
#pragma unroll
    for (int qb = 0; qb < 2; ++qb) {
      const int qr = qloc + qb * 16;
#pragma unroll
      for (int dt = 0; dt < 8; ++dt)
        *(f32x4*)&sm.mrg.O1[qr][lgrp * 4 + dt * 16] = oacc[qb][dt];
      if (lgrp == 0) {
        sm.mrg.m1[qr] = mrun[qb];
        sm.mrg.l1[qr] = lsum[qb];
      }
    }
  }
  __syncthreads();

  // ---- half 0 merges and stores
  if (half == 0) {
#pragma unroll
    for (int qb = 0; qb < 2; ++qb) {
      const int qr = qloc + qb * 16;
      float m1v = sm.mrg.m1[qr];
      float l1v = sm.mrg.l1[qr];
      float m  = fmaxf(mrun[qb], m1v);
      float a0 = fexp2((mrun[qb] - m) * LOG2E);
      float a1 = fexp2((m1v - m) * LOG2E);
      float inv = __builtin_amdgcn_rcpf(lsum[qb] * a0 + l1v * a1);
      float* op = outp + ((size_t)(b * MM + q0 + qb * 16)) * DD + lgrp * 4;
#pragma unroll
      for (int dt = 0; dt < 8; ++dt) {
        f32x4 o1 = *(const f32x4*)&sm.mrg.O1[qr][lgrp * 4 + dt * 16];
        f32x4 v = (oacc[qb][dt] * a0 + o1 * a1) * inv;
        *(f32x4*)(op + dt * 16) = v;
      }
    }
  }
}

extern "C" void kernel_launch(void* const* d_in, const int* in_sizes, int n_in,
                              void* d_out, int out_size, void* d_ws, size_t ws_size,
                              hipStream_t stream) {
  const float* A = (const float*)d_in[0];
  const float* B = (const float*)d_in[1];
  float* out = (float*)d_out;
  if (ws_size < 4 * ARR * sizeof(_Float16)) return;  // need 33.6 MB scratch
  _Float16* ws = (_Float16*)d_ws;

  dim3 g1(16, 32, 2);
  prep_kernel<<<g1, dim3(256, 1, 1), 0, stream>>>(A, B, ws);
  dim3 g2(256, 1, 1);
  attn_kernel<<<g2, dim3(1024, 1, 1), 0, stream>>>(ws, out);
}

// Round 7
// 84.189 us; speedup vs baseline: 3.9272x; 3.9272x over previous
//
#include <hip/hip_runtime.h>
#include <hip/hip_bf16.h>
#include <stdint.h>

typedef __attribute__((ext_vector_type(4))) float f32x4;
typedef __attribute__((ext_vector_type(8))) _Float16 f16x8;
typedef __attribute__((ext_vector_type(2))) __fp16 fp16x2;

#define NB 32
#define MM 1024
#define DD 128
#define BKV 64
#define NTILE (MM / BKV)
#define LOG2E 1.44269504089f
#define RTHR 6.0f

static constexpr size_t ARR = (size_t)NB * MM * DD;  // elems per f16 array

// ws layout (f16): Ah @0, Bh @ARR, VplA @2*ARR, VplB @3*ARR
// Row-major Xh[b][r][128]: 16B chunk c of row r at in-row byte (c*16) ^ ((r&7)<<4)
// Vpl (per-lane V fragments): byte off = ((b*16 + t)<<14) + j*1024 + lane*16,
//   j = 2*dt + kc2; fragment = old sigma_V chunk (ch = kc2*4+lgrp) of row d = dt*16+(lane&15).
//   Wave load of slot j = 64 lanes x 16B contiguous (1KB) — fully coalesced.

__device__ __forceinline__ float fexp2(float x) { return __builtin_amdgcn_exp2f(x); }

__device__ __forceinline__ void gl16(const void* g, void* l) {
  __builtin_amdgcn_global_load_lds((const __attribute__((address_space(1))) void*)g,
                                   (__attribute__((address_space(3))) void*)l, 16, 0, 0);
}

__global__ __launch_bounds__(256) void prep_kernel(const float* __restrict__ A,
                                                   const float* __restrict__ B,
                                                   _Float16* __restrict__ ws) {
  const int rt = blockIdx.x;     // 64-row (kv) tile
  const int b  = blockIdx.y;
  const int wh = blockIdx.z;     // 0=A, 1=B
  const float* __restrict__ src = wh ? B : A;
  _Float16* __restrict__ Xh  = ws + (size_t)wh * ARR;
  _Float16* __restrict__ Vpl = ws + 2 * ARR + (size_t)wh * ARR;

  __shared__ __align__(16) _Float16 tile[64][130];
  const int t = threadIdx.x;

  // phase 1: f32 -> f16, row-major swizzled write + LDS stash
#pragma unroll
  for (int it = 0; it < 4; ++it) {
    int id  = it * 256 + t;
    int row = id >> 4;
    int ch  = id & 15;
    int grow = rt * 64 + row;
    const float* p = src + ((size_t)(b * MM + grow) * DD + ch * 8);
    float4 x0 = *(const float4*)p;
    float4 x1 = *(const float4*)(p + 4);
    f16x8 h;
    h[0] = (_Float16)x0.x; h[1] = (_Float16)x0.y; h[2] = (_Float16)x0.z; h[3] = (_Float16)x0.w;
    h[4] = (_Float16)x1.x; h[5] = (_Float16)x1.y; h[6] = (_Float16)x1.z; h[7] = (_Float16)x1.w;
    char* dst = (char*)Xh + (((size_t)(b * MM + grow)) << 8) + ((ch << 4) ^ ((row & 7) << 4));
    *(f16x8*)dst = h;
#pragma unroll
    for (int j = 0; j < 8; ++j) tile[row][ch * 8 + j] = h[j];
  }
  __syncthreads();

  // phase 2: per-lane V-fragment write (sigma_V content, new placement).
  // sigma_V(i): out5=i5, out4=i2, out3=i4, out2=i3, out1:0=i1:0
#pragma unroll
  for (int it = 0; it < 4; ++it) {
    int id = it * 256 + t;
    int d  = id >> 3;               // 0..127
    int ch = id & 7;                // 0..7
    f16x8 h;
#pragma unroll
    for (int j = 0; j < 8; ++j) {
      int i = ch * 8 + j;
      int s = (i & 0x23) | ((i & 4) << 2) | ((i & 24) >> 1);
      h[j] = tile[s][d];
    }
    int dt = d >> 4, r = d & 15;
    int kc2 = ch >> 2, gq = ch & 3;
    char* dst = (char*)Vpl + (((size_t)(b * 16 + rt)) << 14)
              + (size_t)(dt * 2 + kc2) * 1024 + (size_t)(gq * 16 + r) * 16;
    *(f16x8*)dst = h;
  }
}

__global__ __launch_bounds__(512, 2) void attn_kernel(const _Float16* __restrict__ ws,
                                                      float* __restrict__ out) {
  // XCD-aware decomposition: blocks with same (b,dir) land on same XCD (g%8 fixed)
  const int g   = blockIdx.x;           // 0..511
  const int x   = g & 7;
  const int t2  = g >> 3;
  const int qt  = t2 & 7;               // 0..7 (128-row Q tile)
  const int p   = ((t2 >> 3) << 3) | x; // 0..63 = b + 32*dir
  const int b   = p & 31;
  const int dir = p >> 5;

  const _Float16* __restrict__ Qh  = ws + (dir ? ARR : 0);
  const _Float16* __restrict__ Kh  = ws + (dir ? 0 : ARR);
  const _Float16* __restrict__ Vpl = ws + 2 * ARR + (dir ? 0 : ARR);
  float* __restrict__ outp = out + (size_t)dir * ARR;

  // K-only double buffer (16KB each)
  __shared__ __align__(16) char sbuf[2][16384];

  const int tid  = threadIdx.x;        // 0..511
  const int w    = tid >> 6;           // 0..7
  const int lane = tid & 63;
  const int lrow = lane & 15;
  const int lgrp = lane >> 4;

  const int q0 = qt * 128 + w * 16 + lrow;

  // ---- Q B-fragments (one 16-q block per wave)
  f16x8 qf[4];
  {
    const int swz = (lrow & 7) << 4;
    const char* qbase = (const char*)Qh + (((size_t)(b * MM + q0)) << 8);
#pragma unroll
    for (int kc = 0; kc < 4; ++kc)
      qf[kc] = *(const f16x8*)(qbase + ((kc * 64 + lgrp * 16) ^ swz));
  }

  // ---- per-lane K LDS byte offsets (swizzle folded; kc parity split)
  const int pl  = (lgrp * 16) ^ ((lrow & 3) << 4);
  const int lb6 = (lrow & 4) << 4;
  const int kE = lrow * 256 + pl + lb6;
  const int kO = lrow * 256 + pl + (64 - lb6);

  // ---- staging / V source bases
  const char* ksrc = (const char*)Kh + (((size_t)b * MM) << 8) + (size_t)tid * 16;
  const char* vtb  = (const char*)Vpl + ((size_t)b << 18) + (size_t)lane * 16;

  f32x4 oacc[8];
#pragma unroll
  for (int dt = 0; dt < 8; ++dt) oacc[dt] = (f32x4)0.0f;
  float mrun = -1e30f, lrun = 0.0f;

  // prologue: stage K(0)
  gl16(ksrc, sbuf[0] + tid * 16);
  gl16(ksrc + 8192, sbuf[0] + 8192 + tid * 16);
  asm volatile("s_waitcnt vmcnt(0)" ::: "memory");
  __syncthreads();

#pragma unroll 1
  for (int t = 0; t < NTILE; ++t) {
    const char* base = sbuf[t & 1];

    // 1. issue K(t+1) staging
    if (t + 1 < NTILE) {
      char* sb = sbuf[(t + 1) & 1];
      const char* kp = ksrc + (size_t)(t + 1) * 16384;
      gl16(kp, sb + tid * 16);
      gl16(kp + 8192, sb + 8192 + tid * 16);
    }

    // 2. S^T = mfma(K, Q): rows kv (lgrp*4+r +16nt), col q = lrow
    f32x4 sc[4];
#pragma unroll
    for (int nt = 0; nt < 4; ++nt) sc[nt] = (f32x4)0.0f;
    __builtin_amdgcn_s_setprio(1);
#pragma unroll
    for (int nt = 0; nt < 4; ++nt) {
#pragma unroll
      for (int kc = 0; kc < 4; ++kc) {
        const int off = ((kc & 1) ? kO + (kc - 1) * 64 : kE + kc * 64) + nt * 4096;
        f16x8 kf = *(const f16x8*)(base + off);
        sc[nt] = __builtin_amdgcn_mfma_f32_16x16x32_f16(kf, qf[kc], sc[nt], 0, 0, 0);
      }
    }
    __builtin_amdgcn_s_setprio(0);

    // 3. V batch 0 (slots 0..7) — coalesced 1KB/wave per slot, L1/L2-resident
    f16x8 vreg[16];
    const char* vt = vtb + (size_t)t * 16384;
#pragma unroll
    for (int j = 0; j < 8; ++j) vreg[j] = *(const f16x8*)(vt + j * 1024);

    // 4. softmax: in-lane max check, cross-lane only on trigger
    {
      float a0 = fmaxf(fmaxf(sc[0][0], sc[0][1]), fmaxf(sc[0][2], sc[0][3]));
      float a1 = fmaxf(fmaxf(sc[1][0], sc[1][1]), fmaxf(sc[1][2], sc[1][3]));
      float a2 = fmaxf(fmaxf(sc[2][0], sc[2][1]), fmaxf(sc[2][2], sc[2][3]));
      float a3 = fmaxf(fmaxf(sc[3][0], sc[3][1]), fmaxf(sc[3][2], sc[3][3]));
      float mx = fmaxf(fmaxf(a0, a1), fmaxf(a2, a3));
      if (__any(mx > mrun + RTHR)) {
        float cm = mx;
        cm = fmaxf(cm, __shfl_xor(cm, 16));
        cm = fmaxf(cm, __shfl_xor(cm, 32));
        float mnew = fmaxf(mrun, cm);
        float scale = fexp2((mrun - mnew) * LOG2E);
        lrun *= scale;
#pragma unroll
        for (int dt = 0; dt < 8; ++dt) oacc[dt] *= scale;
        mrun = mnew;
      }
    }

    // 5. P = exp(S-m), pack to f16 B-fragments (sigma_V aligned)
    f16x8 pf[2];
    {
      union { fp16x2 h[8]; f16x8 v[2]; } u;
      float ps = 0.0f;
      const float nml = -mrun * LOG2E;
#pragma unroll
      for (int nt = 0; nt < 4; ++nt) {
        float p0 = fexp2(fmaf(sc[nt][0], LOG2E, nml));
        float p1 = fexp2(fmaf(sc[nt][1], LOG2E, nml));
        float p2 = fexp2(fmaf(sc[nt][2], LOG2E, nml));
        float p3 = fexp2(fmaf(sc[nt][3], LOG2E, nml));
        ps += (p0 + p1) + (p2 + p3);
        u.h[nt * 2 + 0] = __builtin_amdgcn_cvt_pkrtz(p0, p1);
        u.h[nt * 2 + 1] = __builtin_amdgcn_cvt_pkrtz(p2, p3);
      }
      lrun += ps;
      pf[0] = u.v[0];
      pf[1] = u.v[1];
    }

    // 6. V batch 1 (slots 8..15)
#pragma unroll
    for (int j = 8; j < 16; ++j) vreg[j] = *(const f16x8*)(vt + j * 1024);

    // 7. PV: O^T += mfma(V^T, P^T)
    __builtin_amdgcn_s_setprio(1);
#pragma unroll
    for (int dt = 0; dt < 8; ++dt) {
      oacc[dt] = __builtin_amdgcn_mfma_f32_16x16x32_f16(vreg[dt * 2 + 0], pf[0], oacc[dt], 0, 0, 0);
      oacc[dt] = __builtin_amdgcn_mfma_f32_16x16x32_f16(vreg[dt * 2 + 1], pf[1], oacc[dt], 0, 0, 0);
    }
    __builtin_amdgcn_s_setprio(0);

    // 8. K(t+1) landed long ago; cheap drain + barrier
    asm volatile("s_waitcnt vmcnt(0)" ::: "memory");
    __syncthreads();
  }

  // ---- epilogue: combine per-lane l across lgrp, normalize, store
  float l = lrun;
  l += __shfl_xor(l, 16);
  l += __shfl_xor(l, 32);
  float inv = __builtin_amdgcn_rcpf(l);
  float* op = outp + ((size_t)(b * MM + q0)) * DD + lgrp * 4;
#pragma unroll
  for (int dt = 0; dt < 8; ++dt) {
    f32x4 v = oacc[dt] * inv;
    *(f32x4*)(op + dt * 16) = v;
  }
}

extern "C" void kernel_launch(void* const* d_in, const int* in_sizes, int n_in,
                              void* d_out, int out_size, void* d_ws, size_t ws_size,
                              hipStream_t stream) {
  const float* A = (const float*)d_in[0];
  const float* B = (const float*)d_in[1];
  float* out = (float*)d_out;
  if (ws_size < 4 * ARR * sizeof(_Float16)) return;  // need 33.6 MB scratch
  _Float16* ws = (_Float16*)d_ws;

  dim3 g1(16, 32, 2);
  prep_kernel<<<g1, dim3(256, 1, 1), 0, stream>>>(A, B, ws);
  dim3 g2(512, 1, 1);
  attn_kernel<<<g2, dim3(512, 1, 1), 0, stream>>>(ws, out);
}

// Round 8
// 67.474 us; speedup vs baseline: 4.9000x; 1.2477x over previous
//
#include <hip/hip_runtime.h>
#include <hip/hip_bf16.h>
#include <stdint.h>

typedef __attribute__((ext_vector_type(4))) float f32x4;
typedef __attribute__((ext_vector_type(8))) _Float16 f16x8;
typedef __attribute__((ext_vector_type(2))) __fp16 fp16x2;

#define NB 32
#define MM 1024
#define DD 128
#define BKV 64
#define NTILE (MM / BKV)
#define LOG2E 1.44269504089f
#define RTHR 6.0f

static constexpr size_t ARR = (size_t)NB * MM * DD;  // elems per f16 array

// ws layout (f16): Ah @0, Bh @ARR, ATh @2*ARR, BTh @3*ARR
// Row-major Xh[b][r][128]: 16B chunk c of row r at in-row byte (c*16) ^ ((r&7)<<4)
// Transposed XTh[b][d][1024]: per 64-kv (128B) window, chunk c at (c*16) ^ ((d&7)<<4),
//   kv positions sigma_V-permuted (prep phase 2).

__device__ __forceinline__ float fexp2(float x) { return __builtin_amdgcn_exp2f(x); }

__device__ __forceinline__ void gl16(const void* g, void* l) {
  __builtin_amdgcn_global_load_lds((const __attribute__((address_space(1))) void*)g,
                                   (__attribute__((address_space(3))) void*)l, 16, 0, 0);
}

__global__ __launch_bounds__(256) void prep_kernel(const float* __restrict__ A,
                                                   const float* __restrict__ B,
                                                   _Float16* __restrict__ ws) {
  const int rt = blockIdx.x;     // 64-row tile
  const int b  = blockIdx.y;
  const int wh = blockIdx.z;     // 0=A, 1=B
  const float* __restrict__ src = wh ? B : A;
  _Float16* __restrict__ Xh  = ws + (size_t)wh * ARR;
  _Float16* __restrict__ XTh = ws + 2 * ARR + (size_t)wh * ARR;

  __shared__ __align__(16) _Float16 tile[64][130];
  const int t = threadIdx.x;

  // phase 1: f32 -> f16, row-major swizzled write + LDS stash
#pragma unroll
  for (int it = 0; it < 4; ++it) {
    int id  = it * 256 + t;          // 0..1023 (16B chunks)
    int row = id >> 4;               // 0..63
    int ch  = id & 15;
    int grow = rt * 64 + row;
    const float* p = src + ((size_t)(b * MM + grow) * DD + ch * 8);
    float4 x0 = *(const float4*)p;
    float4 x1 = *(const float4*)(p + 4);
    f16x8 h;
    h[0] = (_Float16)x0.x; h[1] = (_Float16)x0.y; h[2] = (_Float16)x0.z; h[3] = (_Float16)x0.w;
    h[4] = (_Float16)x1.x; h[5] = (_Float16)x1.y; h[6] = (_Float16)x1.z; h[7] = (_Float16)x1.w;
    char* dst = (char*)Xh + (((size_t)(b * MM + grow)) << 8) + ((ch << 4) ^ ((row & 7) << 4));
    *(f16x8*)dst = h;
#pragma unroll
    for (int j = 0; j < 8; ++j) tile[row][ch * 8 + j] = h[j];
  }
  __syncthreads();

  // phase 2: transposed, sigma_V-permuted, swizzled write.
  // sigma_V(i): out5=i5, out4=i2, out3=i4, out2=i3, out1:0=i1:0
#pragma unroll
  for (int it = 0; it < 4; ++it) {
    int id = it * 256 + t;           // 0..1023
    int d  = id >> 3;                // 0..127
    int ch = id & 7;                 // 16B chunk within this tile's 64-kv window
    f16x8 h;
#pragma unroll
    for (int j = 0; j < 8; ++j) {
      int i = ch * 8 + j;
      int s = (i & 0x23) | ((i & 4) << 2) | ((i & 24) >> 1);
      h[j] = tile[s][d];
    }
    char* dst = (char*)XTh + (((size_t)(b * DD + d)) << 11) + (rt << 7)
              + ((ch << 4) ^ ((d & 7) << 4));
    *(f16x8*)dst = h;
  }
}

__global__ __launch_bounds__(256, 2) void attn_kernel(const _Float16* __restrict__ ws,
                                                      float* __restrict__ out) {
  // XCD-aware decomposition: blocks with same (b,dir) land on same XCD (g%8 fixed)
  const int g   = blockIdx.x;           // 0..511
  const int x   = g & 7;
  const int t2  = g >> 3;
  const int qt  = t2 & 7;               // 0..7 (128-row Q tile)
  const int p   = ((t2 >> 3) << 3) | x; // 0..63 = b + 32*dir
  const int b   = p & 31;
  const int dir = p >> 5;

  const _Float16* __restrict__ Qh  = ws + (dir ? ARR : 0);
  const _Float16* __restrict__ Kh  = ws + (dir ? 0 : ARR);
  const _Float16* __restrict__ VTh = ws + 2 * ARR + (dir ? 0 : ARR);
  float* __restrict__ outp = out + (size_t)dir * ARR;

  // double buffer: [buf][ K tile 16KB | VT tile 16KB ]
  __shared__ __align__(16) char sbuf[2][32768];

  const int tid  = threadIdx.x;
  const int w    = tid >> 6;
  const int lane = tid & 63;
  const int lrow = lane & 15;
  const int lgrp = lane >> 4;

  const int q0 = qt * 128 + w * 32 + lrow;   // qblk0; qblk1 = q0+16

  // ---- Q B-fragments (both q-blocks), loaded once from global
  f16x8 qf[2][4];
  {
    const int swz = (lrow & 7) << 4;
#pragma unroll
    for (int qb = 0; qb < 2; ++qb) {
      const char* qbase = (const char*)Qh + (((size_t)(b * MM + q0 + qb * 16)) << 8);
#pragma unroll
      for (int kc = 0; kc < 4; ++kc)
        qf[qb][kc] = *(const f16x8*)(qbase + ((kc * 64 + lgrp * 16) ^ swz));
    }
  }

  // ---- per-lane LDS byte-offset bases (swizzle folded; kc parity split)
  const int pl  = (lgrp * 16) ^ ((lrow & 3) << 4);
  const int lb6 = (lrow & 4) << 4;           // 0 or 64
  const int kE = lrow * 256 + pl + lb6;          // K reads, kc even
  const int kO = lrow * 256 + pl + (64 - lb6);   // K reads, kc odd
  const int vE = 16384 + lrow * 128 + pl + lb6;          // VT reads, kc2=0
  const int vO = 16384 + lrow * 128 + pl + (64 - lb6);   // VT reads, kc2=1

  // ---- staging source bases (per-thread)
  const char* ksrc = (const char*)Kh + (((size_t)b * MM) << 8) + (size_t)tid * 16;
  const char* vsrc = (const char*)VTh + (((size_t)b * DD) << 11)
                   + ((size_t)(tid >> 3) << 11) + (size_t)(tid & 7) * 16;

  f32x4 oacc[2][8];
#pragma unroll
  for (int qb = 0; qb < 2; ++qb)
#pragma unroll
    for (int dt = 0; dt < 8; ++dt) oacc[qb][dt] = (f32x4)0.0f;
  float mrun[2] = {-1e30f, -1e30f};
  float lrun[2] = {0.0f, 0.0f};   // per-lane partials (combined in epilogue)

  f16x8 vreg[16];   // V(t) fragments held across the iteration boundary
  f16x8 pf[2][2];   // P(t) fragments (consumed by PV in iteration t+1)

  // prologue: stage tile 0 into buf 0
  {
    char* sb = sbuf[0];
#pragma unroll
    for (int it = 0; it < 4; ++it)
      gl16(ksrc + it * 4096, sb + it * 4096 + tid * 16);
#pragma unroll
    for (int it = 0; it < 4; ++it)
      gl16(vsrc + (size_t)it * 65536, sb + 16384 + it * 4096 + tid * 16);
  }
  asm volatile("s_waitcnt vmcnt(0)" ::: "memory");
  __syncthreads();

#pragma unroll 2
  for (int t = 0; t < NTILE; ++t) {
    const char* base = sbuf[t & 1];

    // 1. issue next tile's staging early (hidden under compute)
    if (t + 1 < NTILE) {
      char* sb = sbuf[(t + 1) & 1];
      const char* kp = ksrc + (size_t)(t + 1) * 16384;
      const char* vp = vsrc + (size_t)(t + 1) * 128;
#pragma unroll
      for (int it = 0; it < 4; ++it)
        gl16(kp + it * 4096, sb + it * 4096 + tid * 16);
#pragma unroll
      for (int it = 0; it < 4; ++it)
        gl16(vp + (size_t)it * 65536, sb + 16384 + it * 4096 + tid * 16);
    }

    // 2. QK(t) and PV(t-1): wave-parity order (role-split so adjacent waves
    //    occupy LDS pipe and MFMA pipe alternately; setprio arbitrates)
    f32x4 sc[2][4];
#pragma unroll
    for (int qb = 0; qb < 2; ++qb)
#pragma unroll
      for (int nt = 0; nt < 4; ++nt) sc[qb][nt] = (f32x4)0.0f;

    auto do_qk = [&]() {
      __builtin_amdgcn_s_setprio(1);
#pragma unroll
      for (int nt = 0; nt < 4; ++nt) {
#pragma unroll
        for (int kc = 0; kc < 4; ++kc) {
          const int off = ((kc & 1) ? kO + (kc - 1) * 64 : kE + kc * 64) + nt * 4096;
          f16x8 kf = *(const f16x8*)(base + off);
          sc[0][nt] = __builtin_amdgcn_mfma_f32_16x16x32_f16(kf, qf[0][kc], sc[0][nt], 0, 0, 0);
          sc[1][nt] = __builtin_amdgcn_mfma_f32_16x16x32_f16(kf, qf[1][kc], sc[1][nt], 0, 0, 0);
        }
      }
      __builtin_amdgcn_s_setprio(0);
    };
    auto do_pv = [&]() {
      if (t > 0) {
        __builtin_amdgcn_s_setprio(1);
#pragma unroll
        for (int dt = 0; dt < 8; ++dt) {
          oacc[0][dt] = __builtin_amdgcn_mfma_f32_16x16x32_f16(vreg[dt * 2 + 0], pf[0][0], oacc[0][dt], 0, 0, 0);
          oacc[0][dt] = __builtin_amdgcn_mfma_f32_16x16x32_f16(vreg[dt * 2 + 1], pf[0][1], oacc[0][dt], 0, 0, 0);
          oacc[1][dt] = __builtin_amdgcn_mfma_f32_16x16x32_f16(vreg[dt * 2 + 0], pf[1][0], oacc[1][dt], 0, 0, 0);
          oacc[1][dt] = __builtin_amdgcn_mfma_f32_16x16x32_f16(vreg[dt * 2 + 1], pf[1][1], oacc[1][dt], 0, 0, 0);
        }
        __builtin_amdgcn_s_setprio(0);
      }
    };
    if (w & 1) { do_pv(); do_qk(); } else { do_qk(); do_pv(); }

    // 3. softmax(t): in-lane max check; cross-lane only on rare trigger
    float mx[2];
#pragma unroll
    for (int qb = 0; qb < 2; ++qb) {
      float a0 = fmaxf(fmaxf(sc[qb][0][0], sc[qb][0][1]), fmaxf(sc[qb][0][2], sc[qb][0][3]));
      float a1 = fmaxf(fmaxf(sc[qb][1][0], sc[qb][1][1]), fmaxf(sc[qb][1][2], sc[qb][1][3]));
      float a2 = fmaxf(fmaxf(sc[qb][2][0], sc[qb][2][1]), fmaxf(sc[qb][2][2], sc[qb][2][3]));
      float a3 = fmaxf(fmaxf(sc[qb][3][0], sc[qb][3][1]), fmaxf(sc[qb][3][2], sc[qb][3][3]));
      mx[qb] = fmaxf(fmaxf(a0, a1), fmaxf(a2, a3));
    }
    bool need = (mx[0] > mrun[0] + RTHR) || (mx[1] > mrun[1] + RTHR);
    if (__any(need)) {
#pragma unroll
      for (int qb = 0; qb < 2; ++qb) {
        float cm = mx[qb];
        cm = fmaxf(cm, __shfl_xor(cm, 16));
        cm = fmaxf(cm, __shfl_xor(cm, 32));
        float mnew = fmaxf(mrun[qb], cm);
        float scale = fexp2((mrun[qb] - mnew) * LOG2E);
        lrun[qb] *= scale;
#pragma unroll
        for (int dt = 0; dt < 8; ++dt) oacc[qb][dt] *= scale;
        mrun[qb] = mnew;
      }
    }

    // 4. P = exp(S - m) in-lane, pack to f16 B-fragments (sigma_V aligned)
#pragma unroll
    for (int qb = 0; qb < 2; ++qb) {
      union { fp16x2 h[8]; f16x8 v[2]; } u;
      float ps = 0.0f;
      const float nml = -mrun[qb] * LOG2E;
#pragma unroll
      for (int nt = 0; nt < 4; ++nt) {
        float p0 = fexp2(fmaf(sc[qb][nt][0], LOG2E, nml));
        float p1 = fexp2(fmaf(sc[qb][nt][1], LOG2E, nml));
        float p2 = fexp2(fmaf(sc[qb][nt][2], LOG2E, nml));
        float p3 = fexp2(fmaf(sc[qb][nt][3], LOG2E, nml));
        ps += (p0 + p1) + (p2 + p3);
        u.h[nt * 2 + 0] = __builtin_amdgcn_cvt_pkrtz(p0, p1);
        u.h[nt * 2 + 1] = __builtin_amdgcn_cvt_pkrtz(p2, p3);
      }
      lrun[qb] += ps;
      pf[qb][0] = u.v[0];
      pf[qb][1] = u.v[1];
    }

    // 5. V(t) LDS -> registers (consumed by PV next iteration)
#pragma unroll
    for (int dt = 0; dt < 8; ++dt) {
      vreg[dt * 2 + 0] = *(const f16x8*)(base + vE + dt * 2048);
      vreg[dt * 2 + 1] = *(const f16x8*)(base + vO + dt * 2048);
    }

    // 6. staging of t+1 landed (issued a full iteration ago); drain + barrier
    asm volatile("s_waitcnt vmcnt(0)" ::: "memory");
    __syncthreads();
  }

  // ---- drain: PV(NTILE-1)
#pragma unroll
  for (int dt = 0; dt < 8; ++dt) {
    oacc[0][dt] = __builtin_amdgcn_mfma_f32_16x16x32_f16(vreg[dt * 2 + 0], pf[0][0], oacc[0][dt], 0, 0, 0);
    oacc[0][dt] = __builtin_amdgcn_mfma_f32_16x16x32_f16(vreg[dt * 2 + 1], pf[0][1], oacc[0][dt], 0, 0, 0);
    oacc[1][dt] = __builtin_amdgcn_mfma_f32_16x16x32_f16(vreg[dt * 2 + 0], pf[1][0], oacc[1][dt], 0, 0, 0);
    oacc[1][dt] = __builtin_amdgcn_mfma_f32_16x16x32_f16(vreg[dt * 2 + 1], pf[1][1], oacc[1][dt], 0, 0, 0);
  }

  // ---- epilogue: combine per-lane l, normalize, store f32x4
#pragma unroll
  for (int qb = 0; qb < 2; ++qb) {
    float l = lrun[qb];
    l += __shfl_xor(l, 16);
    l += __shfl_xor(l, 32);
    float inv = __builtin_amdgcn_rcpf(l);
    float* op = outp + ((size_t)(b * MM + q0 + qb * 16)) * DD + lgrp * 4;
#pragma unroll
    for (int dt = 0; dt < 8; ++dt) {
      f32x4 v = oacc[qb][dt] * inv;
      *(f32x4*)(op + dt * 16) = v;
    }
  }
}

extern "C" void kernel_launch(void* const* d_in, const int* in_sizes, int n_in,
                              void* d_out, int out_size, void* d_ws, size_t ws_size,
                              hipStream_t stream) {
  const float* A = (const float*)d_in[0];
  const float* B = (const float*)d_in[1];
  float* out = (float*)d_out;
  if (ws_size < 4 * ARR * sizeof(_Float16)) return;  // need 33.6 MB scratch
  _Float16* ws = (_Float16*)d_ws;

  dim3 g1(16, 32, 2);
  prep_kernel<<<g1, dim3(256, 1, 1), 0, stream>>>(A, B, ws);
  dim3 g2(512, 1, 1);
  attn_kernel<<<g2, dim3(256, 1, 1), 0, stream>>>(ws, out);
}

// Round 9
// 59.951 us; speedup vs baseline: 5.5149x; 1.1255x over previous
//
#include <hip/hip_runtime.h>
#include <hip/hip_bf16.h>
#include <stdint.h>

typedef __attribute__((ext_vector_type(4))) float f32x4;
typedef __attribute__((ext_vector_type(8))) _Float16 f16x8;
typedef __attribute__((ext_vector_type(2))) __fp16 fp16x2;

#define NB 32
#define MM 1024
#define DD 128
#define BKV 64
#define NTILE (MM / BKV)
#define LOG2E 1.44269504089f
#define RTHR 6.0f

static constexpr size_t ARR = (size_t)NB * MM * DD;  // elems per f16 array

// ws layout (f16): Ah @0, Bh @ARR, ATh @2*ARR, BTh @3*ARR
// Row-major Xh[b][r][128]: 16B chunk c of row r at in-row byte (c*16) ^ ((r&7)<<4)
// Transposed XTh[b][d][1024]: per 64-kv (128B) window, chunk c at (c*16) ^ ((d&7)<<4),
//   kv positions sigma_V-permuted (prep phase 2).

__device__ __forceinline__ float fexp2(float x) { return __builtin_amdgcn_exp2f(x); }

__device__ __forceinline__ void gl16(const void* g, void* l) {
  __builtin_amdgcn_global_load_lds((const __attribute__((address_space(1))) void*)g,
                                   (__attribute__((address_space(3))) void*)l, 16, 0, 0);
}

__global__ __launch_bounds__(256) void prep_kernel(const float* __restrict__ A,
                                                   const float* __restrict__ B,
                                                   _Float16* __restrict__ ws) {
  const int rt = blockIdx.x;     // 64-row tile
  const int b  = blockIdx.y;
  const int wh = blockIdx.z;     // 0=A, 1=B
  const float* __restrict__ src = wh ? B : A;
  _Float16* __restrict__ Xh  = ws + (size_t)wh * ARR;
  _Float16* __restrict__ XTh = ws + 2 * ARR + (size_t)wh * ARR;

  __shared__ __align__(16) _Float16 tile[64][130];
  const int t = threadIdx.x;

  // phase 1: f32 -> f16, row-major swizzled write + LDS stash
#pragma unroll
  for (int it = 0; it < 4; ++it) {
    int id  = it * 256 + t;          // 0..1023 (16B chunks)
    int row = id >> 4;               // 0..63
    int ch  = id & 15;
    int grow = rt * 64 + row;
    const float* p = src + ((size_t)(b * MM + grow) * DD + ch * 8);
    float4 x0 = *(const float4*)p;
    float4 x1 = *(const float4*)(p + 4);
    f16x8 h;
    h[0] = (_Float16)x0.x; h[1] = (_Float16)x0.y; h[2] = (_Float16)x0.z; h[3] = (_Float16)x0.w;
    h[4] = (_Float16)x1.x; h[5] = (_Float16)x1.y; h[6] = (_Float16)x1.z; h[7] = (_Float16)x1.w;
    char* dst = (char*)Xh + (((size_t)(b * MM + grow)) << 8) + ((ch << 4) ^ ((row & 7) << 4));
    *(f16x8*)dst = h;
#pragma unroll
    for (int j = 0; j < 8; ++j) tile[row][ch * 8 + j] = h[j];
  }
  __syncthreads();

  // phase 2: transposed, sigma_V-permuted, swizzled write.
  // sigma_V(i): out5=i5, out4=i2, out3=i4, out2=i3, out1:0=i1:0
#pragma unroll
  for (int it = 0; it < 4; ++it) {
    int id = it * 256 + t;           // 0..1023
    int d  = id >> 3;                // 0..127
    int ch = id & 7;                 // 16B chunk within this tile's 64-kv window
    f16x8 h;
#pragma unroll
    for (int j = 0; j < 8; ++j) {
      int i = ch * 8 + j;
      int s = (i & 0x23) | ((i & 4) << 2) | ((i & 24) >> 1);
      h[j] = tile[s][d];
    }
    char* dst = (char*)XTh + (((size_t)(b * DD + d)) << 11) + (rt << 7)
              + ((ch << 4) ^ ((d & 7) << 4));
    *(f16x8*)dst = h;
  }
}

__global__ __launch_bounds__(256, 2) void attn_kernel(const _Float16* __restrict__ ws,
                                                      float* __restrict__ out) {
  // XCD-aware decomposition: blocks with same (b,dir) land on same XCD (g%8 fixed)
  const int g   = blockIdx.x;           // 0..511
  const int x   = g & 7;
  const int t2  = g >> 3;
  const int qt  = t2 & 7;               // 0..7 (128-row Q tile)
  const int p   = ((t2 >> 3) << 3) | x; // 0..63 = b + 32*dir
  const int b   = p & 31;
  const int dir = p >> 5;

  const _Float16* __restrict__ Qh  = ws + (dir ? ARR : 0);
  const _Float16* __restrict__ Kh  = ws + (dir ? 0 : ARR);
  const _Float16* __restrict__ VTh = ws + 2 * ARR + (dir ? 0 : ARR);
  float* __restrict__ outp = out + (size_t)dir * ARR;

  // double buffer: [buf][ K tile 16KB | VT tile 16KB ]
  __shared__ __align__(16) char sbuf[2][32768];

  const int tid  = threadIdx.x;
  const int w    = tid >> 6;
  const int lane = tid & 63;
  const int lrow = lane & 15;
  const int lgrp = lane >> 4;

  const int q0 = qt * 128 + w * 32 + lrow;   // qblk0; qblk1 = q0+16

  // ---- Q B-fragments (both q-blocks), loaded once from global
  f16x8 qf[2][4];
  {
    const int swz = (lrow & 7) << 4;
#pragma unroll
    for (int qb = 0; qb < 2; ++qb) {
      const char* qbase = (const char*)Qh + (((size_t)(b * MM + q0 + qb * 16)) << 8);
#pragma unroll
      for (int kc = 0; kc < 4; ++kc)
        qf[qb][kc] = *(const f16x8*)(qbase + ((kc * 64 + lgrp * 16) ^ swz));
    }
  }

  // ---- per-lane LDS byte-offset bases (swizzle folded; kc parity split)
  const int pl  = (lgrp * 16) ^ ((lrow & 3) << 4);
  const int lb6 = (lrow & 4) << 4;           // 0 or 64
  const int kE = lrow * 256 + pl + lb6;          // K reads, kc even
  const int kO = lrow * 256 + pl + (64 - lb6);   // K reads, kc odd
  const int vE = 16384 + lrow * 128 + pl + lb6;          // VT reads, kc2=0
  const int vO = 16384 + lrow * 128 + pl + (64 - lb6);   // VT reads, kc2=1

  // ---- staging source bases (per-thread)
  const char* ksrc = (const char*)Kh + (((size_t)b * MM) << 8) + (size_t)tid * 16;
  const char* vsrc = (const char*)VTh + (((size_t)b * DD) << 11)
                   + ((size_t)(tid >> 3) << 11) + (size_t)(tid & 7) * 16;

  f32x4 oacc[2][8];
#pragma unroll
  for (int qb = 0; qb < 2; ++qb)
#pragma unroll
    for (int dt = 0; dt < 8; ++dt) oacc[qb][dt] = (f32x4)0.0f;
  float mrun[2] = {-1e30f, -1e30f};
  float lrun[2] = {0.0f, 0.0f};   // per-lane partials (combined in epilogue)

  f16x8 vreg[16];   // V(t) fragments held across the iteration boundary
  f16x8 pf[2][2];   // P(t) fragments (consumed by PV in iteration t+1)

  // prologue: stage tile 0 into buf 0
  {
    char* sb = sbuf[0];
#pragma unroll
    for (int it = 0; it < 4; ++it)
      gl16(ksrc + it * 4096, sb + it * 4096 + tid * 16);
#pragma unroll
    for (int it = 0; it < 4; ++it)
      gl16(vsrc + (size_t)it * 65536, sb + 16384 + it * 4096 + tid * 16);
  }
  asm volatile("s_waitcnt vmcnt(0)" ::: "memory");
  __syncthreads();

#pragma unroll 1
  for (int t = 0; t < NTILE; ++t) {
    const char* base = sbuf[t & 1];

    // 1. issue next tile's staging early (hidden under compute)
    if (t + 1 < NTILE) {
      char* sb = sbuf[(t + 1) & 1];
      const char* kp = ksrc + (size_t)(t + 1) * 16384;
      const char* vp = vsrc + (size_t)(t + 1) * 128;
#pragma unroll
      for (int it = 0; it < 4; ++it)
        gl16(kp + it * 4096, sb + it * 4096 + tid * 16);
#pragma unroll
      for (int it = 0; it < 4; ++it)
        gl16(vp + (size_t)it * 65536, sb + 16384 + it * 4096 + tid * 16);
    }

    // 2. PV(t-1) FIRST: register-only MFMA right after the barrier — warms the
    //    MFMA pipe with zero LDS pressure while this iteration's K ds_reads
    //    stream underneath (no dependency; compiler interleaves).
    if (t > 0) {
#pragma unroll
      for (int dt = 0; dt < 8; ++dt) {
        oacc[0][dt] = __builtin_amdgcn_mfma_f32_16x16x32_f16(vreg[dt * 2 + 0], pf[0][0], oacc[0][dt], 0, 0, 0);
        oacc[0][dt] = __builtin_amdgcn_mfma_f32_16x16x32_f16(vreg[dt * 2 + 1], pf[0][1], oacc[0][dt], 0, 0, 0);
        oacc[1][dt] = __builtin_amdgcn_mfma_f32_16x16x32_f16(vreg[dt * 2 + 0], pf[1][0], oacc[1][dt], 0, 0, 0);
        oacc[1][dt] = __builtin_amdgcn_mfma_f32_16x16x32_f16(vreg[dt * 2 + 1], pf[1][1], oacc[1][dt], 0, 0, 0);
      }
    }

    // 3. S^T = mfma(K, Q): rows kv (lgrp*4+r +16nt), cols q (lrow)
    f32x4 sc[2][4];
#pragma unroll
    for (int qb = 0; qb < 2; ++qb)
#pragma unroll
      for (int nt = 0; nt < 4; ++nt) sc[qb][nt] = (f32x4)0.0f;
#pragma unroll
    for (int nt = 0; nt < 4; ++nt) {
#pragma unroll
      for (int kc = 0; kc < 4; ++kc) {
        const int off = ((kc & 1) ? kO + (kc - 1) * 64 : kE + kc * 64) + nt * 4096;
        f16x8 kf = *(const f16x8*)(base + off);
        sc[0][nt] = __builtin_amdgcn_mfma_f32_16x16x32_f16(kf, qf[0][kc], sc[0][nt], 0, 0, 0);
        sc[1][nt] = __builtin_amdgcn_mfma_f32_16x16x32_f16(kf, qf[1][kc], sc[1][nt], 0, 0, 0);
      }
    }

    // 4. V(t) LDS -> registers (PV(t-1) already consumed vreg; overlaps softmax)
#pragma unroll
    for (int dt = 0; dt < 8; ++dt) {
      vreg[dt * 2 + 0] = *(const f16x8*)(base + vE + dt * 2048);
      vreg[dt * 2 + 1] = *(const f16x8*)(base + vO + dt * 2048);
    }

    // 5. softmax(t): in-lane max check; cross-lane only on rare trigger
    float mx[2];
#pragma unroll
    for (int qb = 0; qb < 2; ++qb) {
      float a0 = fmaxf(fmaxf(sc[qb][0][0], sc[qb][0][1]), fmaxf(sc[qb][0][2], sc[qb][0][3]));
      float a1 = fmaxf(fmaxf(sc[qb][1][0], sc[qb][1][1]), fmaxf(sc[qb][1][2], sc[qb][1][3]));
      float a2 = fmaxf(fmaxf(sc[qb][2][0], sc[qb][2][1]), fmaxf(sc[qb][2][2], sc[qb][2][3]));
      float a3 = fmaxf(fmaxf(sc[qb][3][0], sc[qb][3][1]), fmaxf(sc[qb][3][2], sc[qb][3][3]));
      mx[qb] = fmaxf(fmaxf(a0, a1), fmaxf(a2, a3));
    }
    bool need = (mx[0] > mrun[0] + RTHR) || (mx[1] > mrun[1] + RTHR);
    if (__any(need)) {
#pragma unroll
      for (int qb = 0; qb < 2; ++qb) {
        float cm = mx[qb];
        cm = fmaxf(cm, __shfl_xor(cm, 16));
        cm = fmaxf(cm, __shfl_xor(cm, 32));
        float mnew = fmaxf(mrun[qb], cm);
        float scale = fexp2((mrun[qb] - mnew) * LOG2E);
        lrun[qb] *= scale;
#pragma unroll
        for (int dt = 0; dt < 8; ++dt) oacc[qb][dt] *= scale;
        mrun[qb] = mnew;
      }
    }

    // 6. P = exp(S - m) in-lane, pack to f16 B-fragments (sigma_V aligned)
#pragma unroll
    for (int qb = 0; qb < 2; ++qb) {
      union { fp16x2 h[8]; f16x8 v[2]; } u;
      float ps = 0.0f;
      const float nml = -mrun[qb] * LOG2E;
#pragma unroll
      for (int nt = 0; nt < 4; ++nt) {
        float p0 = fexp2(fmaf(sc[qb][nt][0], LOG2E, nml));
        float p1 = fexp2(fmaf(sc[qb][nt][1], LOG2E, nml));
        float p2 = fexp2(fmaf(sc[qb][nt][2], LOG2E, nml));
        float p3 = fexp2(fmaf(sc[qb][nt][3], LOG2E, nml));
        ps += (p0 + p1) + (p2 + p3);
        u.h[nt * 2 + 0] = __builtin_amdgcn_cvt_pkrtz(p0, p1);
        u.h[nt * 2 + 1] = __builtin_amdgcn_cvt_pkrtz(p2, p3);
      }
      lrun[qb] += ps;
      pf[qb][0] = u.v[0];
      pf[qb][1] = u.v[1];
    }

    // 7. staging of t+1 landed (issued ~2000cy ago); drain + barrier
    asm volatile("s_waitcnt vmcnt(0)" ::: "memory");
    __syncthreads();
  }

  // ---- drain: PV(NTILE-1)
#pragma unroll
  for (int dt = 0; dt < 8; ++dt) {
    oacc[0][dt] = __builtin_amdgcn_mfma_f32_16x16x32_f16(vreg[dt * 2 + 0], pf[0][0], oacc[0][dt], 0, 0, 0);
    oacc[0][dt] = __builtin_amdgcn_mfma_f32_16x16x32_f16(vreg[dt * 2 + 1], pf[0][1], oacc[0][dt], 0, 0, 0);
    oacc[1][dt] = __builtin_amdgcn_mfma_f32_16x16x32_f16(vreg[dt * 2 + 0], pf[1][0], oacc[1][dt], 0, 0, 0);
    oacc[1][dt] = __builtin_amdgcn_mfma_f32_16x16x32_f16(vreg[dt * 2 + 1], pf[1][1], oacc[1][dt], 0, 0, 0);
  }

  // ---- epilogue: combine per-lane l, normalize, store f32x4
#pragma unroll
  for (int qb = 0; qb < 2; ++qb) {
    float l = lrun[qb];
    l += __shfl_xor(l, 16);
    l += __shfl_xor(l, 32);
    float inv = __builtin_amdgcn_rcpf(l);
    float* op = outp + ((size_t)(b * MM + q0 + qb * 16)) * DD + lgrp * 4;
#pragma unroll
    for (int dt = 0; dt < 8; ++dt) {
      f32x4 v = oacc[qb][dt] * inv;
      *(f32x4*)(op + dt * 16) = v;
    }
  }
}

extern "C" void kernel_launch(void* const* d_in, const int* in_sizes, int n_in,
                              void* d_out, int out_size, void* d_ws, size_t ws_size,
                              hipStream_t stream) {
  const float* A = (const float*)d_in[0];
  const float* B = (const float*)d_in[1];
  float* out = (float*)d_out;
  if (ws_size < 4 * ARR * sizeof(_Float16)) return;  // need 33.6 MB scratch
  _Float16* ws = (_Float16*)d_ws;

  dim3 g1(16, 32, 2);
  prep_kernel<<<g1, dim3(256, 1, 1), 0, stream>>>(A, B, ws);
  dim3 g2(512, 1, 1);
  attn_kernel<<<g2, dim3(256, 1, 1), 0, stream>>>(ws, out);
}